// Round 4
// baseline (552.741 us; speedup 1.0000x reference)
//
#include <hip/hip_runtime.h>
#include <hip/hip_bf16.h>

// Problem: B=512, N_SLOTS=128, IN=2048, MEM=64, OUT=2048.
// Dtype is detected AT RUNTIME (flag in ws): a detector kernel inspects the
// bit patterns of x; every compute kernel is templated on <BF16> and launched
// in both variants, with the mismatching variant early-exiting.
// d_out = [output (512*2048) | new_memory (512*128*64)], same dtype as inputs.

#define NB    512
#define NSLOT 128
#define DIN   2048
#define DMEM  64
#define DOUT  2048
#define PXW   130   // x-projection width: 64 (q) + 1 (forget) + 65 (remember)

typedef __hip_bfloat16 bf16;

template<bool BF16>
__device__ __forceinline__ float ld(const void* p, size_t i) {
  if (BF16) return __bfloat162float(((const bf16*)p)[i]);
  return ((const float*)p)[i];
}
template<bool BF16>
__device__ __forceinline__ void st(void* p, size_t i, float v) {
  if (BF16) ((bf16*)p)[i] = __float2bfloat16(v);
  else      ((float*)p)[i] = v;
}

// ---------------------------------------------------------------------------
// Detector: x has >=1M elements; reading 4096 uint16s is safe for either
// dtype. Little-endian: if data is fp32, even uint16 positions are mantissa
// low-halves (uniform bits -> ~16% "sane" exponent fields); if bf16, even
// positions are real bf16 values of ~N(0,1) (~100% sane). flag=1 => bf16.
// ---------------------------------------------------------------------------
__global__ void k_detect(const void* __restrict__ x, int* __restrict__ flag) {
  __shared__ int cnt;
  if (threadIdx.x == 0) cnt = 0;
  __syncthreads();
  const unsigned short* u = (const unsigned short*)x;
  int sane = 0;
  for (int i = 0; i < 8; ++i) {
    unsigned short v = u[(threadIdx.x * 8 + i) * 2];
    int e = (v >> 7) & 0xFF;
    if (e >= 100 && e <= 140) sane++;
  }
  atomicAdd(&cnt, sane);
  __syncthreads();
  if (threadIdx.x == 0) *flag = (cnt > 1024) ? 1 : 0;
}

// ---------------------------------------------------------------------------
// Kernel 1: px[b][0:130] = x[b] @ [W_ar | W_f[:2048] | W_r[:2048,:]] + biases
// ---------------------------------------------------------------------------
template<bool BF16>
__global__ __launch_bounds__(256) void k_proj_x(
    const int* __restrict__ flag,
    const void* __restrict__ x,
    const void* __restrict__ W_ar, const void* __restrict__ b_ar,
    const void* __restrict__ W_f,  const void* __restrict__ b_f,
    const void* __restrict__ W_r,  const void* __restrict__ b_r,
    float* __restrict__ px) {
  if ((*flag != 0) != BF16) return;
  __shared__ float xs[DIN];
  int b = blockIdx.x;
  for (int k = threadIdx.x; k < DIN; k += 256) xs[k] = ld<BF16>(x, (size_t)b * DIN + k);
  __syncthreads();
  int j = threadIdx.x;
  if (j >= PXW) return;
  const void* wp; size_t base; int stride; float bias;
  if (j < 64)       { wp = W_ar; base = j;      stride = 64; bias = ld<BF16>(b_ar, j); }
  else if (j == 64) { wp = W_f;  base = 0;      stride = 1;  bias = ld<BF16>(b_f, 0); }
  else              { wp = W_r;  base = j - 65; stride = 65; bias = ld<BF16>(b_r, j - 65); }
  float acc = 0.f;
#pragma unroll 8
  for (int k = 0; k < DIN; ++k) acc += xs[k] * ld<BF16>(wp, base + (size_t)k * stride);
  px[b * PXW + j] = acc + bias;
}

// ---------------------------------------------------------------------------
// Kernel 2: per-batch fused — per-slot dots (active/passive scores, forget
// gate, rem col 64), two LDS-tree softmaxes, recalls, gated memory update.
// ---------------------------------------------------------------------------
template<bool BF16>
__global__ __launch_bounds__(256) void k_fused(
    const int* __restrict__ flag,
    const void* __restrict__ memory,
    const void* __restrict__ W_pr, const void* __restrict__ b_pr,
    const void* __restrict__ W_f,  const void* __restrict__ W_r,
    const float* __restrict__ px,
    float* __restrict__ ap,          // [512][128]: active(64) | passive(64)
    void* __restrict__ dout) {       // element index NB*DOUT + ... for new_memory
  if ((*flag != 0) != BF16) return;
  __shared__ float mem_s[NSLOT * 65];
  __shared__ float wrm_s[64 * 68];   // W_r rows 2048..2111, [k][j], j<65
  __shared__ float wfm_s[64], wpr_s[64], qs[64], pxr_s[65];
  __shared__ float sa[128], sp[128], ra[128], rb[128];
  __shared__ float forget_s[128], r64_s[128];

  int b = blockIdx.x, tid = threadIdx.x;
  size_t mb = (size_t)b * (NSLOT * DMEM);
  for (int i = tid; i < NSLOT * DMEM; i += 256)
    mem_s[(i >> 6) * 65 + (i & 63)] = ld<BF16>(memory, mb + i);
  for (int i = tid; i < 64 * 65; i += 256)
    wrm_s[(i / 65) * 68 + (i % 65)] = ld<BF16>(W_r, 2048 * 65 + i);
  if (tid < 64) {
    wfm_s[tid] = ld<BF16>(W_f, 2048 + tid);
    wpr_s[tid] = ld<BF16>(W_pr, tid);
    qs[tid]    = px[b * PXW + tid];
  }
  if (tid < 65) pxr_s[tid] = px[b * PXW + 65 + tid];
  __syncthreads();

  float pxf = px[b * PXW + 64];

  if (tid < 128) {
    const float* mr = &mem_s[tid * 65];
    float aa = 0.f, pp = 0.f, ff = 0.f, rr = 0.f;
#pragma unroll 8
    for (int k = 0; k < 64; ++k) {
      float m = mr[k];
      aa += m * qs[k];
      pp += m * wpr_s[k];
      ff += m * wfm_s[k];
      rr += m * wrm_s[k * 68 + 64];
    }
    sa[tid] = aa;
    sp[tid] = pp + ld<BF16>(b_pr, 0);
    forget_s[tid] = 1.1f / (1.f + __expf(-(ff + pxf)));
    r64_s[tid]    = rr + pxr_s[64];
  }
  __syncthreads();

  // two softmaxes over 128 slots via LDS trees
  if (tid < 128) ra[tid] = sa[tid]; else rb[tid - 128] = sp[tid - 128];
  __syncthreads();
  for (int s = 64; s; s >>= 1) {
    if (tid < s) ra[tid] = fmaxf(ra[tid], ra[tid + s]);
    else if (tid >= 128 && tid < 128 + s) rb[tid - 128] = fmaxf(rb[tid - 128], rb[tid - 128 + s]);
    __syncthreads();
  }
  float mxA = ra[0], mxB = rb[0];
  __syncthreads();
  if (tid < 128) { float e = __expf(sa[tid] - mxA); sa[tid] = e; ra[tid] = e; }
  else           { float e = __expf(sp[tid - 128] - mxB); sp[tid - 128] = e; rb[tid - 128] = e; }
  __syncthreads();
  for (int s = 64; s; s >>= 1) {
    if (tid < s) ra[tid] += ra[tid + s];
    else if (tid >= 128 && tid < 128 + s) rb[tid - 128] += rb[tid - 128 + s];
    __syncthreads();
  }
  float invA = 1.f / ra[0], invB = 1.f / rb[0];
  __syncthreads();
  if (tid < 128) sa[tid] *= invA; else sp[tid - 128] *= invB;
  __syncthreads();

  // recalls: ap[b][0:64]=active, ap[b][64:128]=passive
  if (tid < 128) {
    int m = tid & 63;
    const float* w = (tid < 64) ? sa : sp;
    float acc = 0.f;
#pragma unroll 8
    for (int n = 0; n < NSLOT; ++n) acc += mem_s[n * 65 + m] * w[n];
    ap[b * 128 + tid] = acc;
  }

  // gated memory update: each iteration handles (slot n, cols j0..j0+3)
  size_t obase = (size_t)NB * DOUT + mb;
  for (int Q = tid; Q < NSLOT * 16; Q += 256) {
    int n = Q >> 4, j0 = (Q & 15) * 4;
    const float* mr = &mem_s[n * 65];
    float r0 = 0.f, r1 = 0.f, r2 = 0.f, r3 = 0.f;
#pragma unroll 8
    for (int k = 0; k < 64; ++k) {
      float mv = mr[k];
      const float* wr = &wrm_s[k * 68 + j0];
      r0 += mv * wr[0]; r1 += mv * wr[1]; r2 += mv * wr[2]; r3 += mv * wr[3];
    }
    float fg = forget_s[n], r64 = r64_s[n];
    size_t o = obase + n * DMEM + j0;
    st<BF16>(dout, o + 0, mr[j0 + 0] * fg + r64 * (r0 + pxr_s[j0 + 0]));
    st<BF16>(dout, o + 1, mr[j0 + 1] * fg + r64 * (r1 + pxr_s[j0 + 1]));
    st<BF16>(dout, o + 2, mr[j0 + 2] * fg + r64 * (r2 + pxr_s[j0 + 2]));
    st<BF16>(dout, o + 3, mr[j0 + 3] * fg + r64 * (r3 + pxr_s[j0 + 3]));
  }
}

// ---------------------------------------------------------------------------
// Kernel 3: output = [x | active | passive] @ W_o + b_o   (fp32 tiled GEMM)
// BM=BN=64, BK=16; 256 threads, each computes a 4x4 micro-tile.
// ---------------------------------------------------------------------------
template<bool BF16>
__global__ __launch_bounds__(256) void k_out_gemm(
    const int* __restrict__ flag,
    const void* __restrict__ x, const float* __restrict__ ap,
    const void* __restrict__ Wo, const void* __restrict__ bo,
    void* __restrict__ dout) {
  if ((*flag != 0) != BF16) return;
  __shared__ float As[16 * 68];
  __shared__ float Bs[16 * 68];
  int tid = threadIdx.x;
  int tx = tid & 15, ty = tid >> 4;
  int col0 = blockIdx.x * 64, row0 = blockIdx.y * 64;
  float acc[4][4] = {};
  for (int k0 = 0; k0 < DIN + 2 * DMEM; k0 += 16) {
    for (int i = tid; i < 1024; i += 256) {
      int m = i >> 4, kk = i & 15, k = k0 + kk;
      float v;
      if (k0 < DIN) v = ld<BF16>(x, (size_t)(row0 + m) * DIN + k);
      else          v = ap[(row0 + m) * 128 + (k - DIN)];
      As[kk * 68 + m] = v;
    }
    for (int i = tid; i < 1024; i += 256) {
      int kk = i >> 6, nn = i & 63;
      Bs[kk * 68 + nn] = ld<BF16>(Wo, (size_t)(k0 + kk) * DOUT + col0 + nn);
    }
    __syncthreads();
#pragma unroll
    for (int kk = 0; kk < 16; ++kk) {
      float a[4], bb[4];
#pragma unroll
      for (int i = 0; i < 4; ++i) a[i] = As[kk * 68 + ty * 4 + i];
#pragma unroll
      for (int j = 0; j < 4; ++j) bb[j] = Bs[kk * 68 + tx * 4 + j];
#pragma unroll
      for (int i = 0; i < 4; ++i)
#pragma unroll
        for (int j = 0; j < 4; ++j) acc[i][j] += a[i] * bb[j];
    }
    __syncthreads();
  }
#pragma unroll
  for (int i = 0; i < 4; ++i) {
    int r = row0 + ty * 4 + i;
#pragma unroll
    for (int j = 0; j < 4; ++j) {
      int c = col0 + tx * 4 + j;
      st<BF16>(dout, (size_t)r * DOUT + c, acc[i][j] + ld<BF16>(bo, c));
    }
  }
}

// ---------------------------------------------------------------------------
extern "C" void kernel_launch(void* const* d_in, const int* in_sizes, int n_in,
                              void* d_out, int out_size, void* d_ws, size_t ws_size,
                              hipStream_t stream) {
  const void* x    = d_in[0];
  const void* mem  = d_in[1];
  const void* W_ar = d_in[2];
  const void* b_ar = d_in[3];
  const void* W_pr = d_in[4];
  const void* b_pr = d_in[5];
  const void* W_f  = d_in[6];
  const void* b_f  = d_in[7];
  const void* W_r  = d_in[8];
  const void* b_r  = d_in[9];
  const void* W_o  = d_in[10];
  const void* b_o  = d_in[11];

  int*   flag = (int*)d_ws;
  float* px   = (float*)((char*)d_ws + 16);   // 512*130 floats
  float* ap   = px + NB * PXW;                // 512*128 floats

  k_detect<<<1, 256, 0, stream>>>(x, flag);

  k_proj_x<false><<<NB, 256, 0, stream>>>(flag, x, W_ar, b_ar, W_f, b_f, W_r, b_r, px);
  k_proj_x<true ><<<NB, 256, 0, stream>>>(flag, x, W_ar, b_ar, W_f, b_f, W_r, b_r, px);

  k_fused<false><<<NB, 256, 0, stream>>>(flag, mem, W_pr, b_pr, W_f, W_r, px, ap, d_out);
  k_fused<true ><<<NB, 256, 0, stream>>>(flag, mem, W_pr, b_pr, W_f, W_r, px, ap, d_out);

  dim3 g3(DOUT / 64, NB / 64);
  k_out_gemm<false><<<g3, 256, 0, stream>>>(flag, x, ap, W_o, b_o, d_out);
  k_out_gemm<true ><<<g3, 256, 0, stream>>>(flag, x, ap, W_o, b_o, d_out);
}

// Round 5
// 279.302 us; speedup vs baseline: 1.9790x; 1.9790x over previous
//
#include <hip/hip_runtime.h>
#include <hip/hip_bf16.h>

// Problem: B=512, N_SLOTS=128, IN=2048, MEM=64, OUT=2048.
// Runtime dtype detection (flag in ws): detector inspects bit patterns of x;
// compute kernels templated on <BF16>, both variants launched, mismatch exits.
// Evidence (R4): world is fp32 buffers (bf16-quantized values).
// d_out = [output (512*2048) | new_memory (512*128*64)], input dtype.

#define NB    512
#define NSLOT 128
#define DIN   2048
#define DMEM  64
#define DOUT  2048
#define PXW   130   // x-projection width: 64 (q) + 1 (forget) + 65 (remember)
#define KTOT  (DIN + 2 * DMEM)   // 2176

typedef __hip_bfloat16 bf16;
typedef __attribute__((ext_vector_type(8))) short short8;
typedef __attribute__((ext_vector_type(4))) float f32x4;

template<bool BF16>
__device__ __forceinline__ float ld(const void* p, size_t i) {
  if (BF16) return __bfloat162float(((const bf16*)p)[i]);
  return ((const float*)p)[i];
}
template<bool BF16>
__device__ __forceinline__ void st(void* p, size_t i, float v) {
  if (BF16) ((bf16*)p)[i] = __float2bfloat16(v);
  else      ((float*)p)[i] = v;
}

// f32 -> bf16 bits, round-to-nearest-even (inputs are finite/sane).
__device__ __forceinline__ unsigned short f2bu(float f) {
  unsigned int u = __builtin_bit_cast(unsigned int, f);
  u = (u + 0x7FFFu + ((u >> 16) & 1u)) >> 16;
  return (unsigned short)u;
}

// ---------------------------------------------------------------------------
// Detector: even uint16 positions of x. bf16 data -> sane exponents (~100%);
// f32 data -> even positions are mantissa low-halves (~16% sane). flag=1=bf16.
// ---------------------------------------------------------------------------
__global__ void k_detect(const void* __restrict__ x, int* __restrict__ flag) {
  __shared__ int cnt;
  if (threadIdx.x == 0) cnt = 0;
  __syncthreads();
  const unsigned short* u = (const unsigned short*)x;
  int sane = 0;
  for (int i = 0; i < 8; ++i) {
    unsigned short v = u[(threadIdx.x * 8 + i) * 2];
    int e = (v >> 7) & 0xFF;
    if (e >= 100 && e <= 140) sane++;
  }
  atomicAdd(&cnt, sane);
  __syncthreads();
  if (threadIdx.x == 0) *flag = (cnt > 1024) ? 1 : 0;
}

// ---------------------------------------------------------------------------
// Kernel 1: px[b][0:130] = x[b] @ [W_ar | W_f[:2048] | W_r[:2048,:]] + biases
// ---------------------------------------------------------------------------
template<bool BF16>
__global__ __launch_bounds__(256) void k_proj_x(
    const int* __restrict__ flag,
    const void* __restrict__ x,
    const void* __restrict__ W_ar, const void* __restrict__ b_ar,
    const void* __restrict__ W_f,  const void* __restrict__ b_f,
    const void* __restrict__ W_r,  const void* __restrict__ b_r,
    float* __restrict__ px) {
  if ((*flag != 0) != BF16) return;
  __shared__ float xs[DIN];
  int b = blockIdx.x;
  for (int k = threadIdx.x; k < DIN; k += 256) xs[k] = ld<BF16>(x, (size_t)b * DIN + k);
  __syncthreads();
  int j = threadIdx.x;
  if (j >= PXW) return;
  const void* wp; size_t base; int stride; float bias;
  if (j < 64)       { wp = W_ar; base = j;      stride = 64; bias = ld<BF16>(b_ar, j); }
  else if (j == 64) { wp = W_f;  base = 0;      stride = 1;  bias = ld<BF16>(b_f, 0); }
  else              { wp = W_r;  base = j - 65; stride = 65; bias = ld<BF16>(b_r, j - 65); }
  float acc = 0.f;
#pragma unroll 8
  for (int k = 0; k < DIN; ++k) acc += xs[k] * ld<BF16>(wp, base + (size_t)k * stride);
  px[b * PXW + j] = acc + bias;
}

// ---------------------------------------------------------------------------
// Kernel 2: per-batch fused — per-slot dots, two LDS-tree softmaxes, recalls,
// gated memory update. (Unchanged from R4 — re-profile this round.)
// ---------------------------------------------------------------------------
template<bool BF16>
__global__ __launch_bounds__(256) void k_fused(
    const int* __restrict__ flag,
    const void* __restrict__ memory,
    const void* __restrict__ W_pr, const void* __restrict__ b_pr,
    const void* __restrict__ W_f,  const void* __restrict__ W_r,
    const float* __restrict__ px,
    float* __restrict__ ap,          // [512][128]: active(64) | passive(64)
    void* __restrict__ dout) {
  if ((*flag != 0) != BF16) return;
  __shared__ float mem_s[NSLOT * 65];
  __shared__ float wrm_s[64 * 68];   // W_r rows 2048..2111, [k][j], j<65
  __shared__ float wfm_s[64], wpr_s[64], qs[64], pxr_s[65];
  __shared__ float sa[128], sp[128], ra[128], rb[128];
  __shared__ float forget_s[128], r64_s[128];

  int b = blockIdx.x, tid = threadIdx.x;
  size_t mb = (size_t)b * (NSLOT * DMEM);
  for (int i = tid; i < NSLOT * DMEM; i += 256)
    mem_s[(i >> 6) * 65 + (i & 63)] = ld<BF16>(memory, mb + i);
  for (int i = tid; i < 64 * 65; i += 256)
    wrm_s[(i / 65) * 68 + (i % 65)] = ld<BF16>(W_r, 2048 * 65 + i);
  if (tid < 64) {
    wfm_s[tid] = ld<BF16>(W_f, 2048 + tid);
    wpr_s[tid] = ld<BF16>(W_pr, tid);
    qs[tid]    = px[b * PXW + tid];
  }
  if (tid < 65) pxr_s[tid] = px[b * PXW + 65 + tid];
  __syncthreads();

  float pxf = px[b * PXW + 64];

  if (tid < 128) {
    const float* mr = &mem_s[tid * 65];
    float aa = 0.f, pp = 0.f, ff = 0.f, rr = 0.f;
#pragma unroll 8
    for (int k = 0; k < 64; ++k) {
      float m = mr[k];
      aa += m * qs[k];
      pp += m * wpr_s[k];
      ff += m * wfm_s[k];
      rr += m * wrm_s[k * 68 + 64];
    }
    sa[tid] = aa;
    sp[tid] = pp + ld<BF16>(b_pr, 0);
    forget_s[tid] = 1.1f / (1.f + __expf(-(ff + pxf)));
    r64_s[tid]    = rr + pxr_s[64];
  }
  __syncthreads();

  if (tid < 128) ra[tid] = sa[tid]; else rb[tid - 128] = sp[tid - 128];
  __syncthreads();
  for (int s = 64; s; s >>= 1) {
    if (tid < s) ra[tid] = fmaxf(ra[tid], ra[tid + s]);
    else if (tid >= 128 && tid < 128 + s) rb[tid - 128] = fmaxf(rb[tid - 128], rb[tid - 128 + s]);
    __syncthreads();
  }
  float mxA = ra[0], mxB = rb[0];
  __syncthreads();
  if (tid < 128) { float e = __expf(sa[tid] - mxA); sa[tid] = e; ra[tid] = e; }
  else           { float e = __expf(sp[tid - 128] - mxB); sp[tid - 128] = e; rb[tid - 128] = e; }
  __syncthreads();
  for (int s = 64; s; s >>= 1) {
    if (tid < s) ra[tid] += ra[tid + s];
    else if (tid >= 128 && tid < 128 + s) rb[tid - 128] += rb[tid - 128 + s];
    __syncthreads();
  }
  float invA = 1.f / ra[0], invB = 1.f / rb[0];
  __syncthreads();
  if (tid < 128) sa[tid] *= invA; else sp[tid - 128] *= invB;
  __syncthreads();

  if (tid < 128) {
    int m = tid & 63;
    const float* w = (tid < 64) ? sa : sp;
    float acc = 0.f;
#pragma unroll 8
    for (int n = 0; n < NSLOT; ++n) acc += mem_s[n * 65 + m] * w[n];
    ap[b * 128 + tid] = acc;
  }

  size_t obase = (size_t)NB * DOUT + mb;
  for (int Q = tid; Q < NSLOT * 16; Q += 256) {
    int n = Q >> 4, j0 = (Q & 15) * 4;
    const float* mr = &mem_s[n * 65];
    float r0 = 0.f, r1 = 0.f, r2 = 0.f, r3 = 0.f;
#pragma unroll 8
    for (int k = 0; k < 64; ++k) {
      float mv = mr[k];
      const float* wr = &wrm_s[k * 68 + j0];
      r0 += mv * wr[0]; r1 += mv * wr[1]; r2 += mv * wr[2]; r3 += mv * wr[3];
    }
    float fg = forget_s[n], r64 = r64_s[n];
    size_t o = obase + n * DMEM + j0;
    st<BF16>(dout, o + 0, mr[j0 + 0] * fg + r64 * (r0 + pxr_s[j0 + 0]));
    st<BF16>(dout, o + 1, mr[j0 + 1] * fg + r64 * (r1 + pxr_s[j0 + 1]));
    st<BF16>(dout, o + 2, mr[j0 + 2] * fg + r64 * (r2 + pxr_s[j0 + 2]));
    st<BF16>(dout, o + 3, mr[j0 + 3] * fg + r64 * (r3 + pxr_s[j0 + 3]));
  }
}

// ---------------------------------------------------------------------------
// Staging helpers: 8 contiguous source elements -> 8 bf16 (ushort bits).
// ---------------------------------------------------------------------------
union U8x16 { uint4 v; unsigned short u[8]; };

template<bool BF16>
__device__ __forceinline__ void stage8(const void* src, size_t idx, unsigned short* o) {
  if (BF16) {
    U8x16 t; t.v = *(const uint4*)((const unsigned short*)src + idx);
#pragma unroll
    for (int j = 0; j < 8; ++j) o[j] = t.u[j];
  } else {
    const float4* q = (const float4*)((const float*)src + idx);
    float4 a = q[0], b = q[1];
    o[0] = f2bu(a.x); o[1] = f2bu(a.y); o[2] = f2bu(a.z); o[3] = f2bu(a.w);
    o[4] = f2bu(b.x); o[5] = f2bu(b.y); o[6] = f2bu(b.z); o[7] = f2bu(b.w);
  }
}
__device__ __forceinline__ void stage8_f32(const float* src, unsigned short* o) {
  const float4* q = (const float4*)src;
  float4 a = q[0], b = q[1];
  o[0] = f2bu(a.x); o[1] = f2bu(a.y); o[2] = f2bu(a.z); o[3] = f2bu(a.w);
  o[4] = f2bu(b.x); o[5] = f2bu(b.y); o[6] = f2bu(b.z); o[7] = f2bu(b.w);
}

// ---------------------------------------------------------------------------
// Kernel 3: output = [x | active | passive] @ W_o + b_o  via bf16 MFMA.
// 64x64 tile per block, BK=32, 4 waves in 2x2; each wave: 4 acc tiles 16x16.
// A staged [row][k] (stride 40 bf16, 16B-aligned rows); B staged transposed
// [n][k] (stride 40). Fragment layouts per m89/m91-verified mapping:
//   A: m=lane&15, k=(lane>>4)*8+j ; B: n=lane&15, same k
//   D: col=lane&15, row=(lane>>4)*4+reg
// ---------------------------------------------------------------------------
#define ASTR 40
template<bool BF16>
__global__ __launch_bounds__(256) void k_out_gemm(
    const int* __restrict__ flag,
    const void* __restrict__ x, const float* __restrict__ ap,
    const void* __restrict__ Wo, const void* __restrict__ bo,
    void* __restrict__ dout) {
  if ((*flag != 0) != BF16) return;
  __shared__ unsigned short As[64 * ASTR];
  __shared__ unsigned short Bs[64 * ASTR];
  int tid = threadIdx.x;
  int col0 = blockIdx.x * 64, row0 = blockIdx.y * 64;
  int lane = tid & 63, w = tid >> 6;
  int wm = w >> 1, wn = w & 1;
  int lr = lane & 15, lk = (lane >> 4) * 8;

  // staging indices
  int ar = tid >> 2, akq = (tid & 3) * 8;     // A: row 0..63, k-quad 0,8,16,24
  int bk = tid >> 3, bnq = (tid & 7) * 8;     // B: k 0..31, n-oct 0..56

  f32x4 acc[2][2] = {};

  for (int k0 = 0; k0 < KTOT; k0 += 32) {
    // --- stage A tile: 64 rows x 32 k ---
    {
      unsigned short t8[8];
      if (k0 < DIN) stage8<BF16>(x, (size_t)(row0 + ar) * DIN + k0 + akq, t8);
      else          stage8_f32(ap + (size_t)(row0 + ar) * 128 + (k0 - DIN) + akq, t8);
      U8x16 pk;
#pragma unroll
      for (int j = 0; j < 8; ++j) pk.u[j] = t8[j];
      *(uint4*)&As[ar * ASTR + akq] = pk.v;
    }
    // --- stage B tile transposed: Bs[n][k], n=col0.., k=k0.. ---
    {
      unsigned short t8[8];
      stage8<BF16>(Wo, (size_t)(k0 + bk) * DOUT + col0 + bnq, t8);
#pragma unroll
      for (int j = 0; j < 8; ++j) Bs[(bnq + j) * ASTR + bk] = t8[j];
    }
    __syncthreads();

    short8 a0 = *(const short8*)&As[(wm * 32 + lr) * ASTR + lk];
    short8 a1 = *(const short8*)&As[(wm * 32 + 16 + lr) * ASTR + lk];
    short8 b0 = *(const short8*)&Bs[(wn * 32 + lr) * ASTR + lk];
    short8 b1 = *(const short8*)&Bs[(wn * 32 + 16 + lr) * ASTR + lk];
    acc[0][0] = __builtin_amdgcn_mfma_f32_16x16x32_bf16(a0, b0, acc[0][0], 0, 0, 0);
    acc[0][1] = __builtin_amdgcn_mfma_f32_16x16x32_bf16(a0, b1, acc[0][1], 0, 0, 0);
    acc[1][0] = __builtin_amdgcn_mfma_f32_16x16x32_bf16(a1, b0, acc[1][0], 0, 0, 0);
    acc[1][1] = __builtin_amdgcn_mfma_f32_16x16x32_bf16(a1, b1, acc[1][1], 0, 0, 0);
    __syncthreads();
  }

  // --- epilogue: D col=lane&15, row=(lane>>4)*4+r ---
#pragma unroll
  for (int i = 0; i < 2; ++i) {
#pragma unroll
    for (int j2 = 0; j2 < 2; ++j2) {
      int c = col0 + wn * 32 + j2 * 16 + lr;
      float bias = ld<BF16>(bo, c);
#pragma unroll
      for (int r = 0; r < 4; ++r) {
        int rr = row0 + wm * 32 + i * 16 + (lane >> 4) * 4 + r;
        st<BF16>(dout, (size_t)rr * DOUT + c, acc[i][j2][r] + bias);
      }
    }
  }
}

// ---------------------------------------------------------------------------
extern "C" void kernel_launch(void* const* d_in, const int* in_sizes, int n_in,
                              void* d_out, int out_size, void* d_ws, size_t ws_size,
                              hipStream_t stream) {
  const void* x    = d_in[0];
  const void* mem  = d_in[1];
  const void* W_ar = d_in[2];
  const void* b_ar = d_in[3];
  const void* W_pr = d_in[4];
  const void* b_pr = d_in[5];
  const void* W_f  = d_in[6];
  const void* b_f  = d_in[7];
  const void* W_r  = d_in[8];
  const void* b_r  = d_in[9];
  const void* W_o  = d_in[10];
  const void* b_o  = d_in[11];

  int*   flag = (int*)d_ws;
  float* px   = (float*)((char*)d_ws + 16);   // 512*130 floats
  float* ap   = px + NB * PXW;                // 512*128 floats

  k_detect<<<1, 256, 0, stream>>>(x, flag);

  k_proj_x<false><<<NB, 256, 0, stream>>>(flag, x, W_ar, b_ar, W_f, b_f, W_r, b_r, px);
  k_proj_x<true ><<<NB, 256, 0, stream>>>(flag, x, W_ar, b_ar, W_f, b_f, W_r, b_r, px);

  k_fused<false><<<NB, 256, 0, stream>>>(flag, mem, W_pr, b_pr, W_f, W_r, px, ap, d_out);
  k_fused<true ><<<NB, 256, 0, stream>>>(flag, mem, W_pr, b_pr, W_f, W_r, px, ap, d_out);

  dim3 g3(DOUT / 64, NB / 64);
  k_out_gemm<false><<<g3, 256, 0, stream>>>(flag, x, ap, W_o, b_o, d_out);
  k_out_gemm<true ><<<g3, 256, 0, stream>>>(flag, x, ap, W_o, b_o, d_out);
}

// Round 6
// 238.665 us; speedup vs baseline: 2.3160x; 1.1703x over previous
//
#include <hip/hip_runtime.h>
#include <hip/hip_bf16.h>

// Problem: B=512, N_SLOTS=128, IN=2048, MEM=64, OUT=2048.
// Runtime dtype detection (flag in ws): detector inspects bit patterns of x;
// compute kernels templated on <BF16>, both variants launched, mismatch exits.
// Evidence (R4/R5): world is fp32 buffers holding bf16-quantized values.
// d_out = [output (512*2048) | new_memory (512*128*64)], input dtype.

#define NB    512
#define NSLOT 128
#define DIN   2048
#define DMEM  64
#define DOUT  2048
#define PXW   130   // x-projection width: 64 (q) + 1 (forget) + 65 (remember)
#define KTOT  (DIN + 2 * DMEM)   // 2176

typedef __hip_bfloat16 bf16;
typedef __attribute__((ext_vector_type(8))) short short8;
typedef __attribute__((ext_vector_type(4))) float f32x4;

template<bool BF16>
__device__ __forceinline__ float ld(const void* p, size_t i) {
  if (BF16) return __bfloat162float(((const bf16*)p)[i]);
  return ((const float*)p)[i];
}
template<bool BF16>
__device__ __forceinline__ void st(void* p, size_t i, float v) {
  if (BF16) ((bf16*)p)[i] = __float2bfloat16(v);
  else      ((float*)p)[i] = v;
}

// f32 -> bf16 bits, round-to-nearest-even (inputs are finite/sane).
__device__ __forceinline__ unsigned short f2bu(float f) {
  unsigned int u = __builtin_bit_cast(unsigned int, f);
  u = (u + 0x7FFFu + ((u >> 16) & 1u)) >> 16;
  return (unsigned short)u;
}
// bf16 bits -> f32 (exact)
__device__ __forceinline__ float bu2f(unsigned short u) {
  unsigned int w = ((unsigned int)u) << 16;
  return __builtin_bit_cast(float, w);
}

// ---------------------------------------------------------------------------
// Detector: even uint16 positions of x. bf16 data -> sane exponents (~100%);
// f32 data -> even positions are mantissa low-halves (~16% sane). flag=1=bf16.
// ---------------------------------------------------------------------------
__global__ void k_detect(const void* __restrict__ x, int* __restrict__ flag) {
  __shared__ int cnt;
  if (threadIdx.x == 0) cnt = 0;
  __syncthreads();
  const unsigned short* u = (const unsigned short*)x;
  int sane = 0;
  for (int i = 0; i < 8; ++i) {
    unsigned short v = u[(threadIdx.x * 8 + i) * 2];
    int e = (v >> 7) & 0xFF;
    if (e >= 100 && e <= 140) sane++;
  }
  atomicAdd(&cnt, sane);
  __syncthreads();
  if (threadIdx.x == 0) *flag = (cnt > 1024) ? 1 : 0;
}

// ---------------------------------------------------------------------------
// Kernel 1a: pack the x-side projection weights transposed into Wt[130][2048]
// (bf16 bits). Column j: j<64 -> W_ar[:,j]; j==64 -> W_f[:2048]; j>=65 ->
// W_r[:2048, j-65]. LDS tile transpose, 32 blocks each covering 64 k's.
// ---------------------------------------------------------------------------
template<bool BF16>
__global__ __launch_bounds__(256) void k_packW(
    const int* __restrict__ flag,
    const void* __restrict__ W_ar, const void* __restrict__ W_f,
    const void* __restrict__ W_r,
    unsigned short* __restrict__ Wt) {
  if ((*flag != 0) != BF16) return;
  __shared__ float tile[PXW * 65];
  int k0 = blockIdx.x * 64;
  for (int i = threadIdx.x; i < 64 * PXW; i += 256) {
    int kl = i / PXW, j = i - kl * PXW;
    int k = k0 + kl;
    float v;
    if (j < 64)       v = ld<BF16>(W_ar, (size_t)k * 64 + j);
    else if (j == 64) v = ld<BF16>(W_f, k);
    else              v = ld<BF16>(W_r, (size_t)k * 65 + (j - 65));
    tile[j * 65 + kl] = v;
  }
  __syncthreads();
  for (int i = threadIdx.x; i < PXW * 64; i += 256) {
    int j = i >> 6, kk = i & 63;
    Wt[(size_t)j * DIN + k0 + kk] = f2bu(tile[j * 65 + kk]);
  }
}

// ---------------------------------------------------------------------------
// Kernel 1b: px[b][j] = dot(x[b], Wt[j]) + bias[j]. One block per batch row;
// x row in LDS; each wave handles columns j = wave, wave+4, ...; lanes split
// K (16B coalesced weight loads + ds_read_b128 + 6-step shuffle reduce).
// ---------------------------------------------------------------------------
union U8x16 { uint4 v; unsigned short u[8]; };

template<bool BF16>
__global__ __launch_bounds__(256) void k_proj_dot(
    const int* __restrict__ flag,
    const void* __restrict__ x,
    const unsigned short* __restrict__ Wt,
    const void* __restrict__ b_ar, const void* __restrict__ b_f,
    const void* __restrict__ b_r,
    float* __restrict__ px) {
  if ((*flag != 0) != BF16) return;
  __shared__ float xs[DIN];
  int b = blockIdx.x;
  for (int k = threadIdx.x; k < DIN; k += 256) xs[k] = ld<BF16>(x, (size_t)b * DIN + k);
  __syncthreads();
  int wv = threadIdx.x >> 6, lane = threadIdx.x & 63;
  for (int j = wv; j < PXW; j += 4) {
    const unsigned short* wc = Wt + (size_t)j * DIN;
    float acc = 0.f;
#pragma unroll
    for (int i = 0; i < 4; ++i) {
      int k0 = i * 512 + lane * 8;
      U8x16 t; t.v = *(const uint4*)(wc + k0);
      const float4* xp = (const float4*)&xs[k0];
      float4 xa = xp[0], xb = xp[1];
      acc += xa.x * bu2f(t.u[0]) + xa.y * bu2f(t.u[1])
           + xa.z * bu2f(t.u[2]) + xa.w * bu2f(t.u[3])
           + xb.x * bu2f(t.u[4]) + xb.y * bu2f(t.u[5])
           + xb.z * bu2f(t.u[6]) + xb.w * bu2f(t.u[7]);
    }
#pragma unroll
    for (int off = 32; off; off >>= 1) acc += __shfl_xor(acc, off, 64);
    if (lane == 0) {
      float bias;
      if (j < 64)       bias = ld<BF16>(b_ar, j);
      else if (j == 64) bias = ld<BF16>(b_f, 0);
      else              bias = ld<BF16>(b_r, j - 65);
      px[b * PXW + j] = acc + bias;
    }
  }
}

// ---------------------------------------------------------------------------
// Kernel 2: per-batch fused — per-slot dots, two LDS-tree softmaxes, recalls,
// gated memory update. (Unchanged — profiled next round.)
// ---------------------------------------------------------------------------
template<bool BF16>
__global__ __launch_bounds__(256) void k_fused(
    const int* __restrict__ flag,
    const void* __restrict__ memory,
    const void* __restrict__ W_pr, const void* __restrict__ b_pr,
    const void* __restrict__ W_f,  const void* __restrict__ W_r,
    const float* __restrict__ px,
    float* __restrict__ ap,          // [512][128]: active(64) | passive(64)
    void* __restrict__ dout) {
  if ((*flag != 0) != BF16) return;
  __shared__ float mem_s[NSLOT * 65];
  __shared__ float wrm_s[64 * 68];   // W_r rows 2048..2111, [k][j], j<65
  __shared__ float wfm_s[64], wpr_s[64], qs[64], pxr_s[65];
  __shared__ float sa[128], sp[128], ra[128], rb[128];
  __shared__ float forget_s[128], r64_s[128];

  int b = blockIdx.x, tid = threadIdx.x;
  size_t mb = (size_t)b * (NSLOT * DMEM);
  for (int i = tid; i < NSLOT * DMEM; i += 256)
    mem_s[(i >> 6) * 65 + (i & 63)] = ld<BF16>(memory, mb + i);
  for (int i = tid; i < 64 * 65; i += 256)
    wrm_s[(i / 65) * 68 + (i % 65)] = ld<BF16>(W_r, 2048 * 65 + i);
  if (tid < 64) {
    wfm_s[tid] = ld<BF16>(W_f, 2048 + tid);
    wpr_s[tid] = ld<BF16>(W_pr, tid);
    qs[tid]    = px[b * PXW + tid];
  }
  if (tid < 65) pxr_s[tid] = px[b * PXW + 65 + tid];
  __syncthreads();

  float pxf = px[b * PXW + 64];

  if (tid < 128) {
    const float* mr = &mem_s[tid * 65];
    float aa = 0.f, pp = 0.f, ff = 0.f, rr = 0.f;
#pragma unroll 8
    for (int k = 0; k < 64; ++k) {
      float m = mr[k];
      aa += m * qs[k];
      pp += m * wpr_s[k];
      ff += m * wfm_s[k];
      rr += m * wrm_s[k * 68 + 64];
    }
    sa[tid] = aa;
    sp[tid] = pp + ld<BF16>(b_pr, 0);
    forget_s[tid] = 1.1f / (1.f + __expf(-(ff + pxf)));
    r64_s[tid]    = rr + pxr_s[64];
  }
  __syncthreads();

  if (tid < 128) ra[tid] = sa[tid]; else rb[tid - 128] = sp[tid - 128];
  __syncthreads();
  for (int s = 64; s; s >>= 1) {
    if (tid < s) ra[tid] = fmaxf(ra[tid], ra[tid + s]);
    else if (tid >= 128 && tid < 128 + s) rb[tid - 128] = fmaxf(rb[tid - 128], rb[tid - 128 + s]);
    __syncthreads();
  }
  float mxA = ra[0], mxB = rb[0];
  __syncthreads();
  if (tid < 128) { float e = __expf(sa[tid] - mxA); sa[tid] = e; ra[tid] = e; }
  else           { float e = __expf(sp[tid - 128] - mxB); sp[tid - 128] = e; rb[tid - 128] = e; }
  __syncthreads();
  for (int s = 64; s; s >>= 1) {
    if (tid < s) ra[tid] += ra[tid + s];
    else if (tid >= 128 && tid < 128 + s) rb[tid - 128] += rb[tid - 128 + s];
    __syncthreads();
  }
  float invA = 1.f / ra[0], invB = 1.f / rb[0];
  __syncthreads();
  if (tid < 128) sa[tid] *= invA; else sp[tid - 128] *= invB;
  __syncthreads();

  if (tid < 128) {
    int m = tid & 63;
    const float* w = (tid < 64) ? sa : sp;
    float acc = 0.f;
#pragma unroll 8
    for (int n = 0; n < NSLOT; ++n) acc += mem_s[n * 65 + m] * w[n];
    ap[b * 128 + tid] = acc;
  }

  size_t obase = (size_t)NB * DOUT + mb;
  for (int Q = tid; Q < NSLOT * 16; Q += 256) {
    int n = Q >> 4, j0 = (Q & 15) * 4;
    const float* mr = &mem_s[n * 65];
    float r0 = 0.f, r1 = 0.f, r2 = 0.f, r3 = 0.f;
#pragma unroll 8
    for (int k = 0; k < 64; ++k) {
      float mv = mr[k];
      const float* wr = &wrm_s[k * 68 + j0];
      r0 += mv * wr[0]; r1 += mv * wr[1]; r2 += mv * wr[2]; r3 += mv * wr[3];
    }
    float fg = forget_s[n], r64 = r64_s[n];
    size_t o = obase + n * DMEM + j0;
    st<BF16>(dout, o + 0, mr[j0 + 0] * fg + r64 * (r0 + pxr_s[j0 + 0]));
    st<BF16>(dout, o + 1, mr[j0 + 1] * fg + r64 * (r1 + pxr_s[j0 + 1]));
    st<BF16>(dout, o + 2, mr[j0 + 2] * fg + r64 * (r2 + pxr_s[j0 + 2]));
    st<BF16>(dout, o + 3, mr[j0 + 3] * fg + r64 * (r3 + pxr_s[j0 + 3]));
  }
}

// ---------------------------------------------------------------------------
// Staging helpers for k_out_gemm.
// ---------------------------------------------------------------------------
template<bool BF16>
__device__ __forceinline__ void stage8(const void* src, size_t idx, unsigned short* o) {
  if (BF16) {
    U8x16 t; t.v = *(const uint4*)((const unsigned short*)src + idx);
#pragma unroll
    for (int j = 0; j < 8; ++j) o[j] = t.u[j];
  } else {
    const float4* q = (const float4*)((const float*)src + idx);
    float4 a = q[0], b = q[1];
    o[0] = f2bu(a.x); o[1] = f2bu(a.y); o[2] = f2bu(a.z); o[3] = f2bu(a.w);
    o[4] = f2bu(b.x); o[5] = f2bu(b.y); o[6] = f2bu(b.z); o[7] = f2bu(b.w);
  }
}
__device__ __forceinline__ void stage8_f32(const float* src, unsigned short* o) {
  const float4* q = (const float4*)src;
  float4 a = q[0], b = q[1];
  o[0] = f2bu(a.x); o[1] = f2bu(a.y); o[2] = f2bu(a.z); o[3] = f2bu(a.w);
  o[4] = f2bu(b.x); o[5] = f2bu(b.y); o[6] = f2bu(b.z); o[7] = f2bu(b.w);
}

// ---------------------------------------------------------------------------
// Kernel 3: output = [x | active | passive] @ W_o + b_o  via bf16 MFMA.
// 64x64 tile per block, BK=32, 4 waves in 2x2; each wave: 4 acc tiles 16x16.
// ---------------------------------------------------------------------------
#define ASTR 40
template<bool BF16>
__global__ __launch_bounds__(256) void k_out_gemm(
    const int* __restrict__ flag,
    const void* __restrict__ x, const float* __restrict__ ap,
    const void* __restrict__ Wo, const void* __restrict__ bo,
    void* __restrict__ dout) {
  if ((*flag != 0) != BF16) return;
  __shared__ unsigned short As[64 * ASTR];
  __shared__ unsigned short Bs[64 * ASTR];
  int tid = threadIdx.x;
  int col0 = blockIdx.x * 64, row0 = blockIdx.y * 64;
  int lane = tid & 63, w = tid >> 6;
  int wm = w >> 1, wn = w & 1;
  int lr = lane & 15, lk = (lane >> 4) * 8;

  int ar = tid >> 2, akq = (tid & 3) * 8;     // A: row 0..63, k-quad 0,8,16,24
  int bk = tid >> 3, bnq = (tid & 7) * 8;     // B: k 0..31, n-oct 0..56

  f32x4 acc[2][2] = {};

  for (int k0 = 0; k0 < KTOT; k0 += 32) {
    {
      unsigned short t8[8];
      if (k0 < DIN) stage8<BF16>(x, (size_t)(row0 + ar) * DIN + k0 + akq, t8);
      else          stage8_f32(ap + (size_t)(row0 + ar) * 128 + (k0 - DIN) + akq, t8);
      U8x16 pk;
#pragma unroll
      for (int j = 0; j < 8; ++j) pk.u[j] = t8[j];
      *(uint4*)&As[ar * ASTR + akq] = pk.v;
    }
    {
      unsigned short t8[8];
      stage8<BF16>(Wo, (size_t)(k0 + bk) * DOUT + col0 + bnq, t8);
#pragma unroll
      for (int j = 0; j < 8; ++j) Bs[(bnq + j) * ASTR + bk] = t8[j];
    }
    __syncthreads();

    short8 a0 = *(const short8*)&As[(wm * 32 + lr) * ASTR + lk];
    short8 a1 = *(const short8*)&As[(wm * 32 + 16 + lr) * ASTR + lk];
    short8 b0 = *(const short8*)&Bs[(wn * 32 + lr) * ASTR + lk];
    short8 b1 = *(const short8*)&Bs[(wn * 32 + 16 + lr) * ASTR + lk];
    acc[0][0] = __builtin_amdgcn_mfma_f32_16x16x32_bf16(a0, b0, acc[0][0], 0, 0, 0);
    acc[0][1] = __builtin_amdgcn_mfma_f32_16x16x32_bf16(a0, b1, acc[0][1], 0, 0, 0);
    acc[1][0] = __builtin_amdgcn_mfma_f32_16x16x32_bf16(a1, b0, acc[1][0], 0, 0, 0);
    acc[1][1] = __builtin_amdgcn_mfma_f32_16x16x32_bf16(a1, b1, acc[1][1], 0, 0, 0);
    __syncthreads();
  }

#pragma unroll
  for (int i = 0; i < 2; ++i) {
#pragma unroll
    for (int j2 = 0; j2 < 2; ++j2) {
      int c = col0 + wn * 32 + j2 * 16 + lr;
      float bias = ld<BF16>(bo, c);
#pragma unroll
      for (int r = 0; r < 4; ++r) {
        int rr = row0 + wm * 32 + i * 16 + (lane >> 4) * 4 + r;
        st<BF16>(dout, (size_t)rr * DOUT + c, acc[i][j2][r] + bias);
      }
    }
  }
}

// ---------------------------------------------------------------------------
extern "C" void kernel_launch(void* const* d_in, const int* in_sizes, int n_in,
                              void* d_out, int out_size, void* d_ws, size_t ws_size,
                              hipStream_t stream) {
  const void* x    = d_in[0];
  const void* mem  = d_in[1];
  const void* W_ar = d_in[2];
  const void* b_ar = d_in[3];
  const void* W_pr = d_in[4];
  const void* b_pr = d_in[5];
  const void* W_f  = d_in[6];
  const void* b_f  = d_in[7];
  const void* W_r  = d_in[8];
  const void* b_r  = d_in[9];
  const void* W_o  = d_in[10];
  const void* b_o  = d_in[11];

  int*            flag = (int*)d_ws;
  unsigned short* Wt   = (unsigned short*)((char*)d_ws + 16);        // 130*2048*2
  float*          px   = (float*)((char*)d_ws + 16 + PXW * DIN * 2); // 512*130 f32
  float*          ap   = px + NB * PXW;                              // 512*128 f32

  k_detect<<<1, 256, 0, stream>>>(x, flag);

  k_packW<false><<<DIN / 64, 256, 0, stream>>>(flag, W_ar, W_f, W_r, Wt);
  k_packW<true ><<<DIN / 64, 256, 0, stream>>>(flag, W_ar, W_f, W_r, Wt);

  k_proj_dot<false><<<NB, 256, 0, stream>>>(flag, x, Wt, b_ar, b_f, b_r, px);
  k_proj_dot<true ><<<NB, 256, 0, stream>>>(flag, x, Wt, b_ar, b_f, b_r, px);

  k_fused<false><<<NB, 256, 0, stream>>>(flag, mem, W_pr, b_pr, W_f, W_r, px, ap, d_out);
  k_fused<true ><<<NB, 256, 0, stream>>>(flag, mem, W_pr, b_pr, W_f, W_r, px, ap, d_out);

  dim3 g3(DOUT / 64, NB / 64);
  k_out_gemm<false><<<g3, 256, 0, stream>>>(flag, x, ap, W_o, b_o, d_out);
  k_out_gemm<true ><<<g3, 256, 0, stream>>>(flag, x, ap, W_o, b_o, d_out);
}